// Round 7
// baseline (885.445 us; speedup 1.0000x reference)
//
#include <hip/hip_runtime.h>

typedef unsigned short ushort_t;
typedef __attribute__((ext_vector_type(8))) __bf16 bf16x8;
typedef __attribute__((ext_vector_type(8))) unsigned short ushort8;
typedef __attribute__((ext_vector_type(4))) float floatx4;
typedef __attribute__((ext_vector_type(16))) float floatx16;

#define VN 778
#define KNB 9

__device__ __forceinline__ float bf2f(unsigned short s) {
  union { unsigned int u; float f; } x; x.u = ((unsigned int)s) << 16; return x.f;
}
__device__ __forceinline__ unsigned short f2bf(float f) {
  union { float f; unsigned int u; } x; x.f = f;
  unsigned int r = x.u + 0x7fffu + ((x.u >> 16) & 1u);
  return (unsigned short)(r >> 16);
}

// async global -> LDS, 16B per lane; LDS dest = wave-uniform base + lane*16.
__device__ __forceinline__ void load_lds16(const void* g, void* l) {
  __builtin_amdgcn_global_load_lds(
      (const __attribute__((address_space(1))) unsigned int*)g,
      (__attribute__((address_space(3))) unsigned int*)l, 16, 0, 0);
}

// ---------------- prologue: occ probabilities, finger ids, wh transpose ----
__global__ void prep_misc(const float* __restrict__ pred_occ,
                          const int* f0, const int* f1, const int* f2,
                          const int* f3, const int* f4,
                          int n0, int n1, int n2, int n3, int n4,
                          const float* __restrict__ wh,
                          float* __restrict__ occ, int* __restrict__ fid,
                          float* __restrict__ whT) {
  int t = threadIdx.x;
  for (int i = t; i < 192 * 5; i += 256) {
    int r = i / 5, f = i % 5;
    float p0 = pred_occ[r * 10 + f];
    float p1 = pred_occ[r * 10 + 5 + f];
    occ[i] = 1.0f / (1.0f + __expf(p1 - p0));  // softmax over 2 classes, class 0
  }
  for (int i = t; i < VN; i += 256) fid[i] = -1;
  __syncthreads();
  const int* fp[5] = {f0, f1, f2, f3, f4};
  int fn[5] = {n0, n1, n2, n3, n4};
  for (int fi = 0; fi < 5; ++fi) {  // sequential: later fingers overwrite
    for (int i = t; i < fn[fi]; i += 256) fid[fp[fi][i]] = fi;
    __syncthreads();
  }
  for (int i = t; i < 3 * 2304; i += 256) {
    int o = i / 2304, k = i % 2304;
    whT[i] = wh[k * 3 + o];
  }
}

// ---------------- weighted view mix: wx[b,v,c] (bf16 out) ------------------
__global__ void wx_kernel(const float* __restrict__ x, const float* __restrict__ occ,
                          const int* __restrict__ fid, ushort_t* __restrict__ wx) {
  int g = blockIdx.x * 256 + threadIdx.x;  // 8-ch chunk id over 64*778*32 (exact)
  int c8 = (g & 31) << 3;
  int bv = g >> 5;
  int b = bv / VN;
  int v = bv - b * VN;
  int f = fid[v];
  float w0 = 1.f, w1 = 1.f, w2 = 1.f;
  if (f >= 0) {
    w0 = occ[b * 5 + f];
    w1 = occ[(64 + b) * 5 + f];
    w2 = occ[(128 + b) * 5 + f];
  }
  float m = fmaxf(w0, fmaxf(w1, w2));
  float e0 = __expf(w0 - m), e1 = __expf(w1 - m), e2 = __expf(w2 - m);
  float inv = 1.0f / (e0 + e1 + e2);
  e0 *= inv; e1 *= inv; e2 *= inv;
  size_t base = (size_t)bv * 256 + c8;
  const size_t V1 = (size_t)64 * VN * 256, V2 = (size_t)128 * VN * 256;
  floatx4 x0a = *(const floatx4*)(x + base);
  floatx4 x0b = *(const floatx4*)(x + base + 4);
  floatx4 x1a = *(const floatx4*)(x + V1 + base);
  floatx4 x1b = *(const floatx4*)(x + V1 + base + 4);
  floatx4 x2a = *(const floatx4*)(x + V2 + base);
  floatx4 x2b = *(const floatx4*)(x + V2 + base + 4);
  ushort8 o;
#pragma unroll
  for (int e = 0; e < 4; ++e) {
    o[e]     = f2bf(e0 * x0a[e] + e1 * x1a[e] + e2 * x2a[e]);
    o[e + 4] = f2bf(e0 * x0b[e] + e1 * x1b[e] + e2 * x2b[e]);
  }
  *(ushort8*)(wx + base) = o;
}

// ---------------- x view-0 f32 -> bf16 copy --------------------------------
__global__ void xcvt_kernel(const float* __restrict__ x, ushort_t* __restrict__ xb) {
  int g = blockIdx.x * 256 + threadIdx.x;
  size_t base = (size_t)g * 8;
  floatx4 fa = *(const floatx4*)(x + base);
  floatx4 fb = *(const floatx4*)(x + base + 4);
  ushort8 o;
#pragma unroll
  for (int e = 0; e < 4; ++e) { o[e] = f2bf(fa[e]); o[e + 4] = f2bf(fb[e]); }
  *(ushort8*)(xb + base) = o;
}

// ---------------- pack W[k][n] (f32) into bf16 MFMA B-fragment order --------
// chunk = ((n/32)*(Ktot/16) + k/16)*64 + ((k%16)/8)*32 + (n%32); 8 bf16 (k-contig)
__global__ void pack_w(const float* __restrict__ w, ushort_t* __restrict__ wP,
                       int N, int ksn, int total) {
  int chunk = blockIdx.x * 256 + threadIdx.x;
  if (chunk >= total) return;
  int lane = chunk & 63;
  int rest = chunk >> 6;
  int ks = rest % ksn;
  int tn = rest / ksn;
  int n = (tn << 5) + (lane & 31);
  int kb = (ks << 4) + ((lane >> 5) << 3);
  ushort8 o;
#pragma unroll
  for (int j = 0; j < 8; ++j) o[j] = f2bf(w[(size_t)(kb + j) * N + n]);
  *(ushort8*)(wP + (size_t)chunk * 8) = o;
}

// ---------------- spiral gathered GEMM -------------------------------------
// block = 2 vertices, 256 threads (4 waves); wave tile = 128m(2v x 64b) x 64n.
// Per ks: 4 A ds_read_b128 + 2 B global loads + 8 MFMA (A-LDS reads halved vs
// 32n tile). A double-buffered in 128-ch phases (2 x 32 KB LDS) staged by
// global_load_lds DMA, swizzle on SOURCE side, ONE barrier per phase.
// MODE 0: single bf16 act (rowstride CIN). MODE 1: wx bf16 + x f32 (f32
// phases staged synchronously). MODE 2: wx bf16 + pre-converted bf16 xb.
template <int CIN, int MODE>
__global__ __launch_bounds__(256, 2) void spiral_gemm(
    const ushort_t* __restrict__ act0, const float* __restrict__ actF,
    const ushort_t* __restrict__ actB, const ushort_t* __restrict__ wP,
    const float* __restrict__ bias, const int* __restrict__ idx,
    ushort_t* __restrict__ out, int NOUT) {
  constexpr int H = CIN / 128;       // 128-ch phases per neighbor
  constexpr int P = KNB * H;
  __shared__ __align__(16) ushort_t Alds[2][2048 * 8];   // 2 x 32 KB
  const int v0 = blockIdx.x * 2;
  const int n0 = blockIdx.y << 8;
  const int tid = threadIdx.x;
  const int lane = tid & 63;
  const int wv = tid >> 6;           // 64-n strip (0..3)
  const int mlo = lane & 31;
  const int q = lane >> 5;
  const int xm = mlo & 7;
  floatx16 acc00{}, acc01{}, acc10{}, acc11{}, acc20{}, acc21{}, acc30{}, acc31{};
  const int KtotSteps = KNB * (CIN / 16);
  const int tn0 = (n0 >> 5) + (wv << 1);
  const ushort_t* bp0 = wP + (size_t)tn0 * KtotSteps * 512 + lane * 8;
  const ushort_t* bp1 = bp0 + (size_t)KtotSteps * 512;
  const int* iv0 = idx + v0 * KNB;
  const int* iv1 = iv0 + KNB;
  // LDS elem = vv*8192 + row*128 + slot*8
  const int aoff0 = mlo * 128;
  const int aoff1 = (mlo + 32) * 128;
  const int aoff2 = 8192 + mlo * 128;
  const int aoff3 = 8192 + (mlo + 32) * 128;

  auto dma_stage = [&](int p, ushort_t* buf) {  // bf16 phases only
    const int nbr = p / H, h = p - nbr * H;
    const int nva = iv0[nbr], nvb = iv1[nbr];
#pragma unroll
    for (int it = 0; it < 8; ++it) {
      const int slotb = ((wv << 3) + it) << 6;   // wave-uniform slot base
      const int s = slotb + lane;
      const int vv = s >> 10;
      const int row = (s >> 4) & 63;
      const int ck = (s & 15) ^ (row & 7);       // swizzle on source side
      const int nv = vv ? nvb : nva;
      const ushort_t* src;
      if (MODE == 0) {
        src = act0 + ((size_t)(row * VN + nv)) * CIN + h * 128 + ck * 8;
      } else {
        const ushort_t* basep = (MODE == 1 || h < 2) ? act0 : actB;
        src = basep + ((size_t)(row * VN + nv)) * 256 + (h & 1) * 128 + ck * 8;
      }
      load_lds16(src, buf + (size_t)slotb * 8);
    }
  };
  auto f32_stage = [&](int p, ushort_t* buf) {  // MODE 1, h in {2,3}
    const int nbr = p / H, h = p - nbr * H;
    const int nva = iv0[nbr], nvb = iv1[nbr];
#pragma unroll
    for (int j = 0; j < 8; ++j) {
      const int s = (j << 8) + tid;
      const int vv = s >> 10;
      const int row = (s >> 4) & 63;
      const int ck = (s & 15) ^ (row & 7);
      const int nv = vv ? nvb : nva;
      const float* src = actF + ((size_t)(row * VN + nv)) * 256 + (h - 2) * 128 + ck * 8;
      floatx4 fa = *(const floatx4*)src;
      floatx4 fb = *(const floatx4*)(src + 4);
      ushort8 o;
#pragma unroll
      for (int e = 0; e < 4; ++e) { o[e] = f2bf(fa[e]); o[e + 4] = f2bf(fb[e]); }
      *(ushort8*)(buf + (size_t)s * 8) = o;
    }
  };

  dma_stage(0, Alds[0]);   // phase 0 is always bf16 (h=0)
  __syncthreads();
#pragma unroll 2
  for (int p = 0; p < P; ++p) {
    ushort_t* cur = Alds[p & 1];
    ushort_t* nxt = Alds[(p + 1) & 1];
    const bool have_next = (p + 1 < P);
    const bool next_f32 = (MODE == 1) && (((p + 1) & (H - 1)) >= 2);
    if (have_next && !next_f32) dma_stage(p + 1, nxt);
#pragma unroll
    for (int ks = 0; ks < 8; ++ks) {
      const int cko = ((((ks << 1) + q) ^ xm) << 3);
      bf16x8 a0 = *(const bf16x8*)(cur + aoff0 + cko);
      bf16x8 a1 = *(const bf16x8*)(cur + aoff1 + cko);
      bf16x8 a2 = *(const bf16x8*)(cur + aoff2 + cko);
      bf16x8 a3 = *(const bf16x8*)(cur + aoff3 + cko);
      bf16x8 b0v = *(const bf16x8*)bp0; bp0 += 512;
      bf16x8 b1v = *(const bf16x8*)bp1; bp1 += 512;
      acc00 = __builtin_amdgcn_mfma_f32_32x32x16_bf16(a0, b0v, acc00, 0, 0, 0);
      acc10 = __builtin_amdgcn_mfma_f32_32x32x16_bf16(a1, b0v, acc10, 0, 0, 0);
      acc20 = __builtin_amdgcn_mfma_f32_32x32x16_bf16(a2, b0v, acc20, 0, 0, 0);
      acc30 = __builtin_amdgcn_mfma_f32_32x32x16_bf16(a3, b0v, acc30, 0, 0, 0);
      acc01 = __builtin_amdgcn_mfma_f32_32x32x16_bf16(a0, b1v, acc01, 0, 0, 0);
      acc11 = __builtin_amdgcn_mfma_f32_32x32x16_bf16(a1, b1v, acc11, 0, 0, 0);
      acc21 = __builtin_amdgcn_mfma_f32_32x32x16_bf16(a2, b1v, acc21, 0, 0, 0);
      acc31 = __builtin_amdgcn_mfma_f32_32x32x16_bf16(a3, b1v, acc31, 0, 0, 0);
    }
    __syncthreads();   // drains DMA vmcnt; all waves done reading cur
    if (have_next && next_f32) { f32_stage(p + 1, nxt); __syncthreads(); }
  }
  // epilogue: C/D layout col=lane&31 (=n), row=(reg&3)+8*(reg>>2)+4*(lane>>5)
  const int na = n0 + (wv << 6) + mlo;
  const int nb = na + 32;
  const float bna = bias[na];
  const float bnb = bias[nb];
#pragma unroll
  for (int t = 0; t < 8; ++t) {
    const floatx16 av = (t == 0) ? acc00 : (t == 1) ? acc10 : (t == 2) ? acc20
                      : (t == 3) ? acc30 : (t == 4) ? acc01 : (t == 5) ? acc11
                      : (t == 6) ? acc21 : acc31;
    const int ai = t & 3;                 // A subtile
    const int vcur = v0 + (ai >> 1);
    const int bbase = (ai & 1) << 5;      // row half (+0 / +32)
    const int n = (t < 4) ? na : nb;
    const float bn = (t < 4) ? bna : bnb;
#pragma unroll
    for (int r = 0; r < 16; ++r) {
      const int m = (r & 3) + ((r >> 2) << 3) + (q << 2);
      float val = av[r] + bn; val = val > 0.f ? val : 0.f;
      out[((size_t)((bbase + m) * VN + vcur)) * NOUT + n] = f2bf(val);
    }
  }
}

// ---------------- head: gathered [64 x 2304] @ [2304 x 3], f32 out ---------
__global__ void head_kernel(const ushort_t* __restrict__ act, const float* __restrict__ whT,
                            const float* __restrict__ bh, const int* __restrict__ idx,
                            float* __restrict__ out) {
  __shared__ __align__(16) ushort_t Alds[64 * 256];
  const int v = blockIdx.x;
  const int tid = threadIdx.x;
  float a0 = 0.f, a1 = 0.f, a2 = 0.f;
  const int b = tid;  // valid when tid < 64
  const int xm = b & 7;
  for (int nbr = 0; nbr < KNB; ++nbr) {
    const int nv = idx[v * KNB + nbr];
    __syncthreads();
#pragma unroll
    for (int it = 0; it < 8; ++it) {
      int L = it * 256 + tid;
      int bb = L >> 5;
      int jj = L & 31;
      ushort8 val = *(const ushort8*)(act + ((size_t)(bb * VN + nv)) * 256 + (jj << 3));
      int slot = jj ^ (bb & 7);
      *(ushort8*)&Alds[(size_t)(bb * 32 + slot) * 8] = val;
    }
    __syncthreads();
    if (tid < 64) {
      const float* wp = whT + nbr * 256;
#pragma unroll 4
      for (int j = 0; j < 32; ++j) {
        int jj = j ^ xm;
        ushort8 a8 = *(const ushort8*)&Alds[(b * 32 + jj) * 8];
#pragma unroll
        for (int e = 0; e < 8; ++e) {
          float av = bf2f(a8[e]);
          int k = (j << 3) + e;
          a0 += av * wp[k];
          a1 += av * wp[2304 + k];
          a2 += av * wp[4608 + k];
        }
      }
    }
  }
  if (tid < 64) {
    size_t o = ((size_t)(b * VN + v)) * 3;
    out[o + 0] = a0 + bh[0];
    out[o + 1] = a1 + bh[1];
    out[o + 2] = a2 + bh[2];
  }
}

extern "C" void kernel_launch(void* const* d_in, const int* in_sizes, int n_in,
                              void* d_out, int out_size, void* d_ws, size_t ws_size,
                              hipStream_t stream) {
  const float* x        = (const float*)d_in[0];
  const float* pred_occ = (const float*)d_in[1];
  const int* indices    = (const int*)d_in[2];
  const int* f0 = (const int*)d_in[3];
  const int* f1 = (const int*)d_in[4];
  const int* f2 = (const int*)d_in[5];
  const int* f3 = (const int*)d_in[6];
  const int* f4 = (const int*)d_in[7];
  const float* w0 = (const float*)d_in[8];
  const float* b0 = (const float*)d_in[9];
  const float* w1 = (const float*)d_in[10];
  const float* b1 = (const float*)d_in[11];
  const float* w2 = (const float*)d_in[12];
  const float* b2 = (const float*)d_in[13];
  const float* wh = (const float*)d_in[14];
  const float* bh = (const float*)d_in[15];
  float* outp = (float*)d_out;

  char* ws = (char*)d_ws;
  ushort_t* wP0 = (ushort_t*)(ws + 0);         // 512 x 4608 bf16 (4,718,592 B)
  ushort_t* wP1 = (ushort_t*)(ws + 4718592);   // 256 x 4608 bf16 (2,359,296 B)
  ushort_t* wP2 = (ushort_t*)(ws + 7077888);   // 256 x 2304 bf16 (1,179,648 B)
  float* whT    = (float*)(ws + 8257536);      // 3 x 2304 f32
  float* occ    = (float*)(ws + 8285184);      // 192 x 5 f32
  int* fid      = (int*)(ws + 8289024);        // 778 i32
  ushort_t* R0  = (ushort_t*)(ws + 8292352);   // wx, later h2   [64,V,256] 25.5MB
  ushort_t* R1  = (ushort_t*)(ws + 33785856);  // h1, later h3   [64,V,512] 51MB
  ushort_t* XB  = (ushort_t*)(ws + 84772864);  // optional bf16 x view0, 25.5MB
  const bool useXB = (ws_size >= 110266368ull);

  prep_misc<<<1, 256, 0, stream>>>(pred_occ, f0, f1, f2, f3, f4,
                                   in_sizes[3], in_sizes[4], in_sizes[5],
                                   in_sizes[6], in_sizes[7], wh, occ, fid, whT);
  pack_w<<<294912 / 256, 256, 0, stream>>>(w0, wP0, 512, 288, 294912);
  pack_w<<<147456 / 256, 256, 0, stream>>>(w1, wP1, 256, 288, 147456);
  pack_w<<<73728 / 256, 256, 0, stream>>>(w2, wP2, 256, 144, 73728);
  if (useXB) xcvt_kernel<<<6224, 256, 0, stream>>>(x, XB);
  wx_kernel<<<6224, 256, 0, stream>>>(x, occ, fid, R0);

  // conv0: [wx | x_view0] (512ch) -> h1 (512ch bf16)
  if (useXB)
    spiral_gemm<512, 2><<<dim3(389, 2), 256, 0, stream>>>(R0, nullptr, XB, wP0, b0,
                                                          indices, R1, 512);
  else
    spiral_gemm<512, 1><<<dim3(389, 2), 256, 0, stream>>>(R0, x, nullptr, wP0, b0,
                                                          indices, R1, 512);
  // conv1: h1 (512ch) -> h2 (256ch)
  spiral_gemm<512, 0><<<dim3(389, 1), 256, 0, stream>>>(R1, nullptr, nullptr, wP1, b1,
                                                        indices, R0, 256);
  // conv2: h2 (256ch) -> h3 (256ch)
  spiral_gemm<256, 0><<<dim3(389, 1), 256, 0, stream>>>(R0, nullptr, nullptr, wP2, b2,
                                                        indices, R1, 256);
  // head: h3 -> out [64,V,3] f32
  head_kernel<<<VN, 256, 0, stream>>>(R1, whT, bh, indices, outp);
  (void)n_in; (void)out_size;
}